// Round 7
// baseline (26.879 us; speedup 1.0000x reference)
//
#include <hip/hip_runtime.h>
#include <hip/hip_bf16.h>

// LearnableInterpolation: out[b,t,n] = sum_o softmax_o(-3*(tpos[o,n]-tgt[t])^2) * x[b,o,n]
// B=32, L_org=L_to=2048, N=21. Softmax over o is a near-delta -> 17-tap window.
//
// R7: R6's barrier-free fused kernel, tuned for latency hiding:
//  - BH=8 (2688 blocks, ~10.5/CU -> full wave occupancy, smaller tail)
//  - wave owns 2 batches; ALL 4 gather loads issued before the weight VALU,
//    so exp/fma math runs under global-load latency; single LDS write phase
//  - non-temporal output stores (write-once data, skip L2 allocation)
// Per-thread weights amortized over the wave's 2 batches; no __syncthreads
// anywhere (per-wave LDS slices).

constexpr int LORG  = 2048;
constexpr int LTO   = 2048;
constexpr int NCH   = 21;
constexpr int BATCH = 32;
constexpr int W     = 8;
constexpr int NW    = 2 * W + 1;   // 17 taps
constexpr int TT    = 64;          // t-tile
constexpr int BH    = 8;           // batches per block
constexpr int NBLK  = NCH * (LTO / TT) * (BATCH / BH);   // 21*32*4 = 2688

constexpr float MIN_RATIO = 0.7f, MAX_RATIO = 1.3f;
constexpr float MIN_BIAS  = -4.0f, MAX_BIAS = 4.0f;
constexpr float NEG3LOG2E = -3.0f * 1.4426950408889634f;  // log2-domain scale

__device__ __forceinline__ int compute_o0(float tg, float bb, float ir) {
    const float ocf = (float)LORG + (tg - bb) * ir;
    int o0 = (int)floorf(ocf + 0.5f) - W;
    return max(0, min(LORG - NW, o0));
}

__global__ __launch_bounds__(256) void li_fused(
    const float* __restrict__ x,      // [B, LORG, NCH]
    const float* __restrict__ rmo,    // [NCH]
    const float* __restrict__ bias,   // [NCH]
    float* __restrict__ out)          // [B, LTO, NCH]
{
    // XCD swizzle: 2688 = 8 * 336; consecutive work ids share a t-tile.
    const int h  = blockIdx.x;
    const int wk = (h & 7) * (NBLK / 8) + (h >> 3);
    const int bh = wk & 3;                 // batch quarter
    const int tn = wk >> 2;                // (t-tile, n)
    const int tt = tn / NCH;
    const int n  = tn - tt * NCH;
    const int t0 = tt * TT;

    const int tid = threadIdx.x;
    const int tl  = tid & 63;              // this thread's t within the tile
    const int wv  = tid >> 6;              // wave id 0..3
    const int b0  = bh * BH;

    __shared__ float xs[4][2][128];        // per-wave slices (4 KB)

    const float r  = fminf(fmaxf(rmo[n] + 1.0f, MIN_RATIO), MAX_RATIO);
    const float bb = fminf(fmaxf(bias[n], MIN_BIAS), MAX_BIAS);
    const float ir = 1.0f / r;

    // block-wide window (o0 monotone in t)
    const int lo  = compute_o0((float)(t0 - LTO), bb, ir);
    const int hi  = compute_o0((float)(t0 + TT - 1 - LTO), bb, ir);
    const int len = hi + NW - lo;          // <= ceil(63/0.7)+17 = 107 < 128

    // staging indices (clamped: lo+127 can run past the window)
    const int i0 = min(tl,      len - 1);
    const int i1 = min(tl + 64, len - 1);

    // ---- issue ALL gather loads first (4 in flight; latency hidden under
    //      the weight VALU below) ----
    const int ba = b0 + wv;                // wave's first batch
    const int bc = b0 + wv + 4;            // wave's second batch
    const float* colA = x + ((size_t)(ba * LORG + lo)) * NCH + n;
    const float* colC = x + ((size_t)(bc * LORG + lo)) * NCH + n;
    const float a0 = colA[(size_t)i0 * NCH];
    const float a1 = colA[(size_t)i1 * NCH];
    const float c0 = colC[(size_t)i0 * NCH];
    const float c1 = colC[(size_t)i1 * NCH];

    // ---- per-thread weights for its tl (overlaps load latency) ----
    const float tg = (float)(t0 + tl - LTO);
    const int   o0 = compute_o0(tg, bb, ir);
    const int base = o0 - lo;
    float d = (float)(o0 - LORG) * r + bb - tg;      // d_j = d + j*r
    // analytic max of -3*d_j^2 over j in [0,16]: nearest j to -d/r
    float js = floorf(-d * ir + 0.5f);
    js = fminf(fmaxf(js, 0.0f), 16.0f);
    const float dstar = d + js * r;
    const float m = NEG3LOG2E * dstar * dstar;       // log2-domain max
    float w[NW];
    float s = 0.0f;
    #pragma unroll
    for (int j = 0; j < NW; ++j) {
        const float e = NEG3LOG2E * d * d - m;       // <= 0
        w[j] = exp2f(e);                             // native v_exp_f32
        s += w[j];
        d += r;
    }
    const float inv = 1.0f / s;                      // s >= 1, no NaN

    // ---- LDS write phase (waits arrive here; no block barrier needed) ----
    xs[wv][0][tl]      = a0;
    xs[wv][0][tl + 64] = a1;
    xs[wv][1][tl]      = c0;
    xs[wv][1][tl + 64] = c1;

    // ---- compute both batches ----
    float accA = 0.0f, accC = 0.0f;
    #pragma unroll
    for (int j = 0; j < NW; ++j) {
        accA = fmaf(w[j], xs[wv][0][base + j], accA);
        accC = fmaf(w[j], xs[wv][1][base + j], accC);
    }
    __builtin_nontemporal_store(accA * inv,
        out + ((size_t)ba * LTO + t0 + tl) * NCH + n);
    __builtin_nontemporal_store(accC * inv,
        out + ((size_t)bc * LTO + t0 + tl) * NCH + n);
}

extern "C" void kernel_launch(void* const* d_in, const int* in_sizes, int n_in,
                              void* d_out, int out_size, void* d_ws, size_t ws_size,
                              hipStream_t stream) {
    const float* x    = (const float*)d_in[0];
    const float* rmo  = (const float*)d_in[1];
    const float* bias = (const float*)d_in[2];
    float* out = (float*)d_out;

    li_fused<<<NBLK, 256, 0, stream>>>(x, rmo, bias, out);
}

// Round 8
// 16.932 us; speedup vs baseline: 1.5874x; 1.5874x over previous
//
#include <hip/hip_runtime.h>
#include <hip/hip_bf16.h>

// LearnableInterpolation: out[b,t,n] = sum_o softmax_o(-3*(tpos[o,n]-tgt[t])^2) * x[b,o,n]
// B=32, L_org=L_to=2048, N=21. Softmax over o is a near-delta -> 17-tap window.
//
// R8: R6 structure (BH=16, 4 batches/wave, barrier-free per-wave LDS,
// weights amortized x4) + R7's issue-early idea done right:
//  - ALL 8 gather loads (4 batches x 2 elements) issued at kernel start;
//    weight VALU (~90 ops incl 17 exp2) runs under their latency;
//  - each batch's ds_write happens just before its compute (counted vmcnt);
//  - REGULAR stores (R7's nontemporal stores bypassed L2 write-coalescing:
//    1.38M scattered 4B stores -> 64B HBM RMW each, +10us. Reverted.)

constexpr int LORG  = 2048;
constexpr int LTO   = 2048;
constexpr int NCH   = 21;
constexpr int BATCH = 32;
constexpr int W     = 8;
constexpr int NW    = 2 * W + 1;   // 17 taps
constexpr int TT    = 64;          // t-tile
constexpr int BH    = 16;          // batches per block
constexpr int NBLK  = NCH * (LTO / TT) * (BATCH / BH);   // 21*32*2 = 1344

constexpr float MIN_RATIO = 0.7f, MAX_RATIO = 1.3f;
constexpr float MIN_BIAS  = -4.0f, MAX_BIAS = 4.0f;
constexpr float NEG3LOG2E = -3.0f * 1.4426950408889634f;  // log2-domain scale

__device__ __forceinline__ int compute_o0(float tg, float bb, float ir) {
    const float ocf = (float)LORG + (tg - bb) * ir;
    int o0 = (int)floorf(ocf + 0.5f) - W;
    return max(0, min(LORG - NW, o0));
}

__global__ __launch_bounds__(256) void li_fused(
    const float* __restrict__ x,      // [B, LORG, NCH]
    const float* __restrict__ rmo,    // [NCH]
    const float* __restrict__ bias,   // [NCH]
    float* __restrict__ out)          // [B, LTO, NCH]
{
    // XCD swizzle: 1344 = 8 * 168; consecutive work ids share a t-tile.
    const int h  = blockIdx.x;
    const int wk = (h & 7) * (NBLK / 8) + (h >> 3);
    const int bh = wk & 1;                 // batch half
    const int tn = wk >> 1;                // (t-tile, n)
    const int tt = tn / NCH;
    const int n  = tn - tt * NCH;
    const int t0 = tt * TT;

    const int tid = threadIdx.x;
    const int tl  = tid & 63;              // this thread's t within the tile
    const int wv  = tid >> 6;              // wave id 0..3
    const int b0  = bh * BH;

    __shared__ float xs[4][4][128];        // [wave][batch-slot][elem] (8 KB)

    const float r  = fminf(fmaxf(rmo[n] + 1.0f, MIN_RATIO), MAX_RATIO);
    const float bb = fminf(fmaxf(bias[n], MIN_BIAS), MAX_BIAS);
    const float ir = 1.0f / r;

    // block-wide window (o0 monotone in t)
    const int lo  = compute_o0((float)(t0 - LTO), bb, ir);
    const int hi  = compute_o0((float)(t0 + TT - 1 - LTO), bb, ir);
    const int len = hi + NW - lo;          // <= ceil(63/0.7)+17 = 107 < 128

    // staging indices (clamped: tl+64 can run past the window end)
    const int i0 = min(tl,      len - 1);
    const int i1 = min(tl + 64, len - 1);

    // ---- issue ALL 8 gather loads upfront (latency hidden under weights) --
    const int bA = b0 + wv;                // wave's batches: bA, +4, +8, +12
    const float* colA = x + ((size_t)((bA    ) * LORG + lo)) * NCH + n;
    const float* colB = x + ((size_t)((bA + 4) * LORG + lo)) * NCH + n;
    const float* colC = x + ((size_t)((bA + 8) * LORG + lo)) * NCH + n;
    const float* colD = x + ((size_t)((bA +12) * LORG + lo)) * NCH + n;
    const float a0 = colA[(size_t)i0 * NCH], a1 = colA[(size_t)i1 * NCH];
    const float e0 = colB[(size_t)i0 * NCH], e1 = colB[(size_t)i1 * NCH];
    const float c0 = colC[(size_t)i0 * NCH], c1 = colC[(size_t)i1 * NCH];
    const float d0 = colD[(size_t)i0 * NCH], d1 = colD[(size_t)i1 * NCH];

    // ---- per-thread weights for its tl (overlaps load latency) ----
    const float tg = (float)(t0 + tl - LTO);
    const int   o0 = compute_o0(tg, bb, ir);
    const int base = o0 - lo;
    float d = (float)(o0 - LORG) * r + bb - tg;      // d_j = d + j*r
    // analytic max of -3*d_j^2 over j in [0,16]: nearest j to -d/r
    float js = floorf(-d * ir + 0.5f);
    js = fminf(fmaxf(js, 0.0f), 16.0f);
    const float dstar = d + js * r;
    const float m = NEG3LOG2E * dstar * dstar;       // log2-domain max
    float w[NW];
    float s = 0.0f;
    #pragma unroll
    for (int j = 0; j < NW; ++j) {
        const float e = NEG3LOG2E * d * d - m;       // <= 0
        w[j] = exp2f(e);                             // native v_exp_f32
        s += w[j];
        d += r;
    }
    const float inv = 1.0f / s;                      // s >= 1, no NaN

    // ---- per-batch: ds_write just-in-time (counted vmcnt), compute, store --
    float acc;

    xs[wv][0][tl] = a0; xs[wv][0][tl + 64] = a1;
    acc = 0.0f;
    #pragma unroll
    for (int j = 0; j < NW; ++j) acc = fmaf(w[j], xs[wv][0][base + j], acc);
    out[((size_t)(bA) * LTO + t0 + tl) * NCH + n] = acc * inv;

    xs[wv][1][tl] = e0; xs[wv][1][tl + 64] = e1;
    acc = 0.0f;
    #pragma unroll
    for (int j = 0; j < NW; ++j) acc = fmaf(w[j], xs[wv][1][base + j], acc);
    out[((size_t)(bA + 4) * LTO + t0 + tl) * NCH + n] = acc * inv;

    xs[wv][2][tl] = c0; xs[wv][2][tl + 64] = c1;
    acc = 0.0f;
    #pragma unroll
    for (int j = 0; j < NW; ++j) acc = fmaf(w[j], xs[wv][2][base + j], acc);
    out[((size_t)(bA + 8) * LTO + t0 + tl) * NCH + n] = acc * inv;

    xs[wv][3][tl] = d0; xs[wv][3][tl + 64] = d1;
    acc = 0.0f;
    #pragma unroll
    for (int j = 0; j < NW; ++j) acc = fmaf(w[j], xs[wv][3][base + j], acc);
    out[((size_t)(bA + 12) * LTO + t0 + tl) * NCH + n] = acc * inv;
}

extern "C" void kernel_launch(void* const* d_in, const int* in_sizes, int n_in,
                              void* d_out, int out_size, void* d_ws, size_t ws_size,
                              hipStream_t stream) {
    const float* x    = (const float*)d_in[0];
    const float* rmo  = (const float*)d_in[1];
    const float* bias = (const float*)d_in[2];
    float* out = (float*)d_out;

    li_fused<<<NBLK, 256, 0, stream>>>(x, rmo, bias, out);
}

// Round 9
// 16.319 us; speedup vs baseline: 1.6471x; 1.0376x over previous
//
#include <hip/hip_runtime.h>
#include <hip/hip_bf16.h>

// LearnableInterpolation: out[b,t,n] = sum_o softmax_o(-3*(tpos[o,n]-tgt[t])^2) * x[b,o,n]
// B=32, L_org=L_to=2048, N=21. Softmax over o is a near-delta -> 17-tap window.
//
// R9: R6/R8 structure, occupancy fix. R6's grid (1344 blocks) capped the CU
// at 21/32 waves — latency-bound on ~200cy scattered L2 reads. BH=8 doubles
// the grid (2688 blocks, 10.5/CU -> full 32 waves/CU; LDS 4KB, 8 blocks/CU
// resident). Wave owns 2 batches: all 4 gather loads issued upfront, the
// 17-exp2 weight VALU runs under their latency, single LDS-write phase, then
// both batches computed. Regular stores (R7: NT stores on scattered 4B = +10us,
// never again). Barrier-free per-wave LDS slices throughout.

constexpr int LORG  = 2048;
constexpr int LTO   = 2048;
constexpr int NCH   = 21;
constexpr int BATCH = 32;
constexpr int W     = 8;
constexpr int NW    = 2 * W + 1;   // 17 taps
constexpr int TT    = 64;          // t-tile
constexpr int BH    = 8;           // batches per block (2 per wave)
constexpr int NBLK  = NCH * (LTO / TT) * (BATCH / BH);   // 21*32*4 = 2688

constexpr float MIN_RATIO = 0.7f, MAX_RATIO = 1.3f;
constexpr float MIN_BIAS  = -4.0f, MAX_BIAS = 4.0f;
constexpr float NEG3LOG2E = -3.0f * 1.4426950408889634f;  // log2-domain scale

__device__ __forceinline__ int compute_o0(float tg, float bb, float ir) {
    const float ocf = (float)LORG + (tg - bb) * ir;
    int o0 = (int)floorf(ocf + 0.5f) - W;
    return max(0, min(LORG - NW, o0));
}

__global__ __launch_bounds__(256) void li_fused(
    const float* __restrict__ x,      // [B, LORG, NCH]
    const float* __restrict__ rmo,    // [NCH]
    const float* __restrict__ bias,   // [NCH]
    float* __restrict__ out)          // [B, LTO, NCH]
{
    // XCD swizzle: 2688 = 8 * 336; consecutive work ids share a t-tile, so
    // the ~16 n-blocks reading the same x lines land on one XCD's L2.
    const int h  = blockIdx.x;
    const int wk = (h & 7) * (NBLK / 8) + (h >> 3);
    const int bh = wk & 3;                 // batch quarter
    const int tn = wk >> 2;                // (t-tile, n)
    const int tt = tn / NCH;
    const int n  = tn - tt * NCH;
    const int t0 = tt * TT;

    const int tid = threadIdx.x;
    const int tl  = tid & 63;              // this thread's t within the tile
    const int wv  = tid >> 6;              // wave id 0..3
    const int b0  = bh * BH;

    __shared__ float xs[4][2][128];        // [wave][batch-slot][elem] (4 KB)

    const float r  = fminf(fmaxf(rmo[n] + 1.0f, MIN_RATIO), MAX_RATIO);
    const float bb = fminf(fmaxf(bias[n], MIN_BIAS), MAX_BIAS);
    const float ir = 1.0f / r;

    // block-wide window (o0 monotone in t)
    const int lo  = compute_o0((float)(t0 - LTO), bb, ir);
    const int hi  = compute_o0((float)(t0 + TT - 1 - LTO), bb, ir);
    const int len = hi + NW - lo;          // <= ceil(63/0.7)+17 = 107 < 128

    // staging indices (clamped: tl+64 can run past the window end)
    const int i0 = min(tl,      len - 1);
    const int i1 = min(tl + 64, len - 1);

    // ---- issue ALL 4 gather loads upfront (latency hidden under weights) --
    const int bA = b0 + wv;                // wave's batches: bA, bA+4
    const float* colA = x + ((size_t)((bA    ) * LORG + lo)) * NCH + n;
    const float* colB = x + ((size_t)((bA + 4) * LORG + lo)) * NCH + n;
    const float a0 = colA[(size_t)i0 * NCH], a1 = colA[(size_t)i1 * NCH];
    const float c0 = colB[(size_t)i0 * NCH], c1 = colB[(size_t)i1 * NCH];

    // ---- per-thread weights for its tl (overlaps load latency) ----
    const float tg = (float)(t0 + tl - LTO);
    const int   o0 = compute_o0(tg, bb, ir);
    const int base = o0 - lo;
    float d = (float)(o0 - LORG) * r + bb - tg;      // d_j = d + j*r
    // analytic max of -3*d_j^2 over j in [0,16]: nearest j to -d/r
    float js = floorf(-d * ir + 0.5f);
    js = fminf(fmaxf(js, 0.0f), 16.0f);
    const float dstar = d + js * r;
    const float m = NEG3LOG2E * dstar * dstar;       // log2-domain max
    float w[NW];
    float s = 0.0f;
    #pragma unroll
    for (int j = 0; j < NW; ++j) {
        const float e = NEG3LOG2E * d * d - m;       // <= 0
        w[j] = exp2f(e);                             // native v_exp_f32
        s += w[j];
        d += r;
    }
    const float inv = 1.0f / s;                      // s >= 1, no NaN

    // ---- LDS write phase (vmcnt waits land here), then compute both ----
    xs[wv][0][tl]      = a0;
    xs[wv][0][tl + 64] = a1;
    xs[wv][1][tl]      = c0;
    xs[wv][1][tl + 64] = c1;

    float accA = 0.0f, accB = 0.0f;
    #pragma unroll
    for (int j = 0; j < NW; ++j) {
        accA = fmaf(w[j], xs[wv][0][base + j], accA);
        accB = fmaf(w[j], xs[wv][1][base + j], accB);
    }
    out[((size_t)(bA    ) * LTO + t0 + tl) * NCH + n] = accA * inv;
    out[((size_t)(bA + 4) * LTO + t0 + tl) * NCH + n] = accB * inv;
}

extern "C" void kernel_launch(void* const* d_in, const int* in_sizes, int n_in,
                              void* d_out, int out_size, void* d_ws, size_t ws_size,
                              hipStream_t stream) {
    const float* x    = (const float*)d_in[0];
    const float* rmo  = (const float*)d_in[1];
    const float* bias = (const float*)d_in[2];
    float* out = (float*)d_out;

    li_fused<<<NBLK, 256, 0, stream>>>(x, rmo, bias, out);
}